// Round 16
// baseline (215.276 us; speedup 1.0000x reference)
//
#include <hip/hip_runtime.h>
#include <math.h>

// Problem constants
#define NRAYS        32768
#define MARCH_ITERS  64
#define EPS_         1e-4f
#define STEP_        ((1.0f + 1.0f/64.0f) / 64.0f)   // exact in fp32

typedef __attribute__((ext_vector_type(8)))  short    short8;   // 8 bf16
typedef __attribute__((ext_vector_type(4)))  float    float4v;  // C/D frag
typedef __attribute__((ext_vector_type(4)))  unsigned uint4v;

__device__ __forceinline__ short8 mk_frag(unsigned p0, unsigned p1,
                                          unsigned p2, unsigned p3) {
    uint4v v = {p0, p1, p2, p3};
    return __builtin_bit_cast(short8, v);
}

// One v_perm_b32: low16 = trunc-bf16(a), high16 = trunc-bf16(b).
__device__ __forceinline__ unsigned packbf(unsigned a, unsigned b) {
    return __builtin_amdgcn_perm(b, a, 0x07060302u);
}

// Exact 3-way truncation split: x == hi + mid + lo bit-exactly in fp32.
struct Split3 { unsigned h, m, l; };
__device__ __forceinline__ Split3 split3(float x) {
    unsigned xu = __float_as_uint(x);
    float xh = __uint_as_float(xu & 0xFFFF0000u);
    float r  = x - xh;                        // exact
    unsigned ru = __float_as_uint(r);
    float xm = __uint_as_float(ru & 0xFFFF0000u);
    float r2 = r - xm;                        // exact, fits bf16
    return { xu, ru, __float_as_uint(r2) };
}

// 2-way split: hi + residual (packbf of r truncates -> the mid limb).
struct Split2 { unsigned h, r; };
__device__ __forceinline__ Split2 split2(float x) {
    unsigned xu = __float_as_uint(x);
    float xh = __uint_as_float(xu & 0xFFFF0000u);
    float rr = x - xh;                        // exact residual
    return { xu, __float_as_uint(rr) };
}

// R16: load-balanced 3-wave blocks over 32 rays.
//   wave0 = march group A (16 rays), wave1 = march group B (16 rays),
//   wave2 = tput scan for BOTH groups sequentially (130 evals).
// March wave-time ~= 2x tput wave-time per group (R15 occupancy decay), so
// 1 tput wave per 2 march waves retires simultaneously -> sustained
// 12 waves/CU instead of 16-decaying-to-8. W1 limbs staged in LDS
// (wave0 -> mid, wave1 -> hi; one __syncthreads), one copy per block.
// MFMA layouts (R6-verified): A[row=lane&15][k=quad*8+j],
// B[k=quad*8+j][col=lane&15], C/D col=lane&15 row=quad*4+reg.
// L1 hidden assignment H(t,q,r)=32*(t>>1)+8q+4*(t&1)+r -> in-lane C1->B2.
// Precision: march L2 = 3 products (m,h)(h,m)(h,h); tput L2 = 2 products.
__global__ __launch_bounds__(192, 3) void sdf_3w_k(
    const float* __restrict__ rays,
    const float* __restrict__ W0,  const float* __restrict__ b0,
    const float* __restrict__ W1,  const float* __restrict__ b1,
    const float* __restrict__ W2,  const float* __restrict__ b2,
    const float* __restrict__ Wr0, const float* __restrict__ br0,
    const float* __restrict__ Wr1, const float* __restrict__ br1,
    float* __restrict__ out)
{
    __shared__ uint4v a2mLds[8 * 64];         // 8 KB: W1 mid-limb frags
    __shared__ uint4v a2hLds[8 * 64];         // 8 KB: W1 hi-limb frags

    const int lane   = threadIdx.x & 63;
    const int waveId = threadIdx.x >> 6;      // 0,1 = march; 2 = tput
    const int quad   = lane >> 4;
    const int m      = lane & 15;

    // ---- A1: exact W0^T/b0 limbs, uniform per-quad K-slots (R9-verified) ----
    short8 A1[4];
    {
        const float* wbase = (quad == 0) ? W0 : (quad == 1) ? (W0 + 64)
                           : (quad == 2) ? (W0 + 128) : b0;
        #pragma unroll
        for (int t = 0; t < 4; ++t) {
            int j = 32 * (t >> 1) + 8 * (m >> 2) + 4 * (t & 1) + (m & 3);
            Split3 s = split3(wbase[j]);
            unsigned hh = packbf(s.h, s.h);
            unsigned hm = packbf(s.h, s.m);
            unsigned ml = packbf(s.m, s.l);
            unsigned l0 = packbf(s.l, 0u);
            bool is3 = (quad == 3);
            A1[t] = mk_frag(is3 ? hm : hh, is3 ? l0 : hm, is3 ? 0u : ml, 0u);
        }
    }

    // ---- cooperative W1 limb staging: wave0 -> a2m, wave1 -> a2h ----
    if (waveId == 0) {
        #pragma unroll
        for (int h = 0; h < 2; ++h)
            #pragma unroll
            for (int t = 0; t < 4; ++t) {
                unsigned pm[4];
                #pragma unroll
                for (int jp = 0; jp < 4; ++jp) {
                    int k0 = 32 * h + quad * 8 + 2 * jp;
                    int j2 = 16 * t + m;
                    Split2 a = split2(W1[k0 * 64 + j2]);
                    Split2 b = split2(W1[(k0 + 1) * 64 + j2]);
                    pm[jp] = packbf(a.r, b.r);   // trunc(residual) == mid limb
                }
                a2mLds[(h * 4 + t) * 64 + lane] = (uint4v){pm[0], pm[1], pm[2], pm[3]};
            }
    } else if (waveId == 1) {
        #pragma unroll
        for (int h = 0; h < 2; ++h)
            #pragma unroll
            for (int t = 0; t < 4; ++t) {
                unsigned ph[4];
                #pragma unroll
                for (int jp = 0; jp < 4; ++jp) {
                    int k0 = 32 * h + quad * 8 + 2 * jp;
                    int j2 = 16 * t + m;
                    ph[jp] = packbf(__float_as_uint(W1[k0 * 64 + j2]),
                                    __float_as_uint(W1[(k0 + 1) * 64 + j2]));
                }
                a2hLds[(h * 4 + t) * 64 + lane] = (uint4v){ph[0], ph[1], ph[2], ph[3]};
            }
    }
    __syncthreads();                           // one-time; loops are sync-free

    // ---- b1 (C2 init) and W2 (L3), per-lane rows j2 = 16t+4q+r ----
    float4v b1v[4], w2v[4];
    #pragma unroll
    for (int t = 0; t < 4; ++t) {
        int base = 16 * t + 4 * quad;
        b1v[t] = (float4v){b1[base], b1[base + 1], b1[base + 2], b1[base + 3]};
        w2v[t] = (float4v){W2[base], W2[base + 1], W2[base + 2], W2[base + 3]};
    }
    const float b2s = b2[0];
    const float4v z4 = {0.f, 0.f, 0.f, 0.f};

    // ---- branchless exact B1 build (R9/R10-verified) ----
    auto buildB1 = [&](float px, float py, float pz) -> short8 {
        float c = (quad == 0) ? px : (quad == 1) ? py : pz;
        Split3 s = split3(c);
        unsigned d0 = packbf(s.h, s.m);
        unsigned d1 = packbf(s.l, s.h);
        unsigned d2 = packbf(s.m, s.h);
        if (quad == 3) { d0 = 0x3F803F80u; d1 = 0x00003F80u; d2 = 0u; }
        return mk_frag(d0, d1, d2, 0u);
    };

    // ---- shared front-end: pos -> exact L1 -> relu -> split2 pack ----
    auto front = [&](float px, float py, float pz, short8* BH, short8* BM) {
        short8 B1 = buildB1(px, py, pz);
        float4v C1[4];
        #pragma unroll
        for (int t = 0; t < 4; ++t)
            C1[t] = __builtin_amdgcn_mfma_f32_16x16x32_bf16(A1[t], B1, z4, 0, 0, 0);
        unsigned PH[4][2], PM[4][2];
        #pragma unroll
        for (int t = 0; t < 4; ++t) {
            float v0 = fmaxf(C1[t][0], 0.f), v1 = fmaxf(C1[t][1], 0.f);
            float v2 = fmaxf(C1[t][2], 0.f), v3 = fmaxf(C1[t][3], 0.f);
            unsigned u0 = __float_as_uint(v0), u1 = __float_as_uint(v1);
            unsigned u2 = __float_as_uint(v2), u3 = __float_as_uint(v3);
            PH[t][0] = packbf(u0, u1); PH[t][1] = packbf(u2, u3);
            float r0 = v0 - __uint_as_float(u0 & 0xFFFF0000u);
            float r1 = v1 - __uint_as_float(u1 & 0xFFFF0000u);
            float r2 = v2 - __uint_as_float(u2 & 0xFFFF0000u);
            float r3 = v3 - __uint_as_float(u3 & 0xFFFF0000u);
            PM[t][0] = packbf(__float_as_uint(r0), __float_as_uint(r1));
            PM[t][1] = packbf(__float_as_uint(r2), __float_as_uint(r3));
        }
        #pragma unroll
        for (int h = 0; h < 2; ++h) {
            BH[h] = mk_frag(PH[2 * h][0], PH[2 * h][1],
                            PH[2 * h + 1][0], PH[2 * h + 1][1]);
            BM[h] = mk_frag(PM[2 * h][0], PM[2 * h][1],
                            PM[2 * h + 1][0], PM[2 * h + 1][1]);
        }
    };

    // ---- L3: in-lane relu*W2, 2 cross-quad shuffles -> d at every lane ----
    auto l3 = [&](const float4v* C2) -> float {
        float q0 = 0.f, q1 = 0.f, q2 = 0.f, q3 = 0.f;
        #pragma unroll
        for (int t = 0; t < 4; ++t) {
            q0 = fmaf(fmaxf(C2[t][0], 0.f), w2v[t][0], q0);
            q1 = fmaf(fmaxf(C2[t][1], 0.f), w2v[t][1], q1);
            q2 = fmaf(fmaxf(C2[t][2], 0.f), w2v[t][2], q2);
            q3 = fmaf(fmaxf(C2[t][3], 0.f), w2v[t][3], q3);
        }
        float part = (q0 + q1) + (q2 + q3);
        part += __shfl_xor(part, 16, 64);
        part += __shfl_xor(part, 32, 64);
        return b2s + part;
    };

    auto ldsFrag = [&](const uint4v* base, int h, int t) -> short8 {
        return __builtin_bit_cast(short8, base[(h * 4 + t) * 64 + lane]);
    };

    if (waveId < 2) {
        // =================== MARCH wave: one 16-ray group ==================
        const int rayBase = blockIdx.x * 32 + waveId * 16;
        const float* rp = rays + (rayBase + m) * 6;
        const float ox = rp[0], oy = rp[1], oz = rp[2];
        const float dx = rp[3], dy = rp[4], dz = rp[5];

        bool  hit = false;
        float cd  = 0.f;
        #pragma unroll 1
        for (int it = 0; it < MARCH_ITERS; ++it) {
            if (__all(hit)) break;
            short8 BH[2], BM[2];
            front(fmaf(dx, cd, ox), fmaf(dy, cd, oy), fmaf(dz, cd, oz), BH, BM);
            // L2: 3 products, small first: (m,h)(h,m)(h,h); 24 MFMAs.
            float4v C2[4];
            #pragma unroll
            for (int t = 0; t < 4; ++t) C2[t] = b1v[t];
            #pragma unroll
            for (int h = 0; h < 2; ++h)
                #pragma unroll
                for (int t = 0; t < 4; ++t)
                    C2[t] = __builtin_amdgcn_mfma_f32_16x16x32_bf16(
                        ldsFrag(a2mLds, h, t), BH[h], C2[t], 0, 0, 0);
            #pragma unroll
            for (int h = 0; h < 2; ++h)
                #pragma unroll
                for (int t = 0; t < 4; ++t)
                    C2[t] = __builtin_amdgcn_mfma_f32_16x16x32_bf16(
                        ldsFrag(a2hLds, h, t), BM[h], C2[t], 0, 0, 0);
            #pragma unroll
            for (int h = 0; h < 2; ++h)
                #pragma unroll
                for (int t = 0; t < 4; ++t)
                    C2[t] = __builtin_amdgcn_mfma_f32_16x16x32_bf16(
                        ldsFrag(a2hLds, h, t), BH[h], C2[t], 0, 0, 0);
            float dm = l3(C2);
            bool c = (dm < EPS_) && (cd >= 0.f) && (cd <= 1.f);
            hit = hit || c;
            if (!hit) cd += dm;
        }

        // ---- reflection net: quad q handles hidden j in [16q, 16q+16) ----
        const float px = fmaf(dx, cd, ox), py = fmaf(dy, cd, oy), pz = fmaf(dz, cd, oz);
        float r0 = 0.f, r1 = 0.f, r2 = 0.f;
        #pragma unroll 4
        for (int jj = 0; jj < 16; ++jj) {
            int j = quad * 16 + jj;
            float a = fmaf(px, Wr0[j],
                      fmaf(py, Wr0[64 + j],
                      fmaf(pz, Wr0[128 + j],
                      fmaf(dx, Wr0[192 + j],
                      fmaf(dy, Wr0[256 + j],
                      fmaf(dz, Wr0[320 + j], br0[j]))))));
            a = fmaxf(a, 0.f);
            r0 = fmaf(a, Wr1[j * 3 + 0], r0);
            r1 = fmaf(a, Wr1[j * 3 + 1], r1);
            r2 = fmaf(a, Wr1[j * 3 + 2], r2);
        }
        r0 += __shfl_xor(r0, 16, 64); r0 += __shfl_xor(r0, 32, 64);
        r1 += __shfl_xor(r1, 16, 64); r1 += __shfl_xor(r1, 32, 64);
        r2 += __shfl_xor(r2, 16, 64); r2 += __shfl_xor(r2, 32, 64);
        r0 = 1.f / (1.f + expf(-(r0 + br1[0])));
        r1 = 1.f / (1.f + expf(-(r1 + br1[1])));
        r2 = 1.f / (1.f + expf(-(r2 + br1[2])));
        if (!hit) { r0 = 0.f; r1 = 0.f; r2 = 0.f; }
        if (lane < 16) {
            float* op = out + (rayBase + lane) * 4;
            op[0] = r0; op[1] = r1; op[2] = r2;
        }
    } else {
        // ============ TPUT wave: both 16-ray groups, sequentially ==========
        #pragma unroll 1
        for (int g = 0; g < 2; ++g) {
            const int rayBase = blockIdx.x * 32 + g * 16;
            const float* rp = rays + (rayBase + m) * 6;
            const float ox = rp[0], oy = rp[1], oz = rp[2];
            const float dx = rp[3], dy = rp[4], dz = rp[5];

            float cm = 3.4e38f;
            #pragma unroll 1
            for (int i = 0; i <= 64; ++i) {
                float ti = STEP_ * (float)i;
                short8 BH[2], BM[2];
                front(fmaf(dx, ti, ox), fmaf(dy, ti, oy), fmaf(dz, ti, oz), BH, BM);
                // L2: 2 products (h,m)(h,h); 16 MFMAs; A2h streams from LDS.
                float4v C2[4];
                #pragma unroll
                for (int t = 0; t < 4; ++t) C2[t] = b1v[t];
                #pragma unroll
                for (int h = 0; h < 2; ++h)
                    #pragma unroll
                    for (int t = 0; t < 4; ++t)
                        C2[t] = __builtin_amdgcn_mfma_f32_16x16x32_bf16(
                            ldsFrag(a2hLds, h, t), BM[h], C2[t], 0, 0, 0);
                #pragma unroll
                for (int h = 0; h < 2; ++h)
                    #pragma unroll
                    for (int t = 0; t < 4; ++t)
                        C2[t] = __builtin_amdgcn_mfma_f32_16x16x32_bf16(
                            ldsFrag(a2hLds, h, t), BH[h], C2[t], 0, 0, 0);
                float dt = l3(C2);
                cm = fminf(cm, dt);
            }
            if (lane < 16)
                out[(rayBase + lane) * 4 + 3] = cm;
        }
    }
}

extern "C" void kernel_launch(void* const* d_in, const int* in_sizes, int n_in,
                              void* d_out, int out_size, void* d_ws, size_t ws_size,
                              hipStream_t stream) {
    const float* rays = (const float*)d_in[0];
    const float* W0   = (const float*)d_in[1];
    const float* b0   = (const float*)d_in[2];
    const float* W1   = (const float*)d_in[3];
    const float* b1   = (const float*)d_in[4];
    const float* W2   = (const float*)d_in[5];
    const float* b2   = (const float*)d_in[6];
    const float* Wr0  = (const float*)d_in[7];
    const float* br0  = (const float*)d_in[8];
    const float* Wr1  = (const float*)d_in[9];
    const float* br1  = (const float*)d_in[10];
    float* out = (float*)d_out;

    // 1024 blocks x 192 threads (32 rays/block): wave0/1 = march A/B,
    // wave2 = tput for both groups — durations matched, so all 3 waves
    // retire together (sustained 12 waves/CU). W1 limbs in LDS (16 KB/blk).
    hipLaunchKernelGGL(sdf_3w_k, dim3(NRAYS / 32), dim3(192), 0, stream,
                       rays, W0, b0, W1, b1, W2, b2, Wr0, br0, Wr1, br1, out);
}